// Round 3
// baseline (6744.109 us; speedup 1.0000x reference)
//
#include <hip/hip_runtime.h>
#include <stdint.h>
#include <stddef.h>

// ---------------------------------------------------------------------------
// CounterfactualDiffusion: 50 sequential steps of 4-layer MLP (258->512->512
// ->512->128) + DDPM update with JAX partitionable-threefry noise, batch 8192.
// Persistent kernel: 256 WGs x 1024 threads (16 waves = 4/SIMD), each WG owns
// 32 rows for all 50 steps. Weights stream from L2 (1.57MB bf16, pre-
// transposed [N][K]); activations live in LDS; x-state in registers.
// Wave w: mtile = w>>3 (rows mtile*16..+16), ntile = w&7 (64-col slice).
// ---------------------------------------------------------------------------

typedef __bf16 bf16;
typedef __bf16 bf16x4 __attribute__((ext_vector_type(4)));
typedef __bf16 bf16x8 __attribute__((ext_vector_type(8)));
typedef float  floatx4 __attribute__((ext_vector_type(4)));

#define NSTEPS    50
#define WG_ROWS   32
#define XB_STRIDE 136   // 128 + 8 pad (16B-aligned rows)
#define H_STRIDE  520   // 512 + 8 pad

__device__ __forceinline__ uint32_t rotl32(uint32_t x, int r) {
  return (x << r) | (x >> (32 - r));
}

// JAX threefry-2x32, 20 rounds.
__device__ __forceinline__ void threefry2x32(uint32_t k0, uint32_t k1,
                                             uint32_t x0, uint32_t x1,
                                             uint32_t& o0, uint32_t& o1) {
  uint32_t k2 = k0 ^ k1 ^ 0x1BD11BDAu;
  x0 += k0; x1 += k1;
#define TF_R(R) { x0 += x1; x1 = rotl32(x1, R); x1 ^= x0; }
  TF_R(13) TF_R(15) TF_R(26) TF_R(6)
  x0 += k1; x1 += k2 + 1u;
  TF_R(17) TF_R(29) TF_R(16) TF_R(24)
  x0 += k2; x1 += k0 + 2u;
  TF_R(13) TF_R(15) TF_R(26) TF_R(6)
  x0 += k0; x1 += k1 + 3u;
  TF_R(17) TF_R(29) TF_R(16) TF_R(24)
  x0 += k1; x1 += k2 + 4u;
  TF_R(13) TF_R(15) TF_R(26) TF_R(6)
  x0 += k2; x1 += k0 + 5u;
#undef TF_R
  o0 = x0; o1 = x1;
}

// XLA's ErfInv32 (Giles) — matches lax.erf_inv f32 path.
__device__ __forceinline__ float erfinv_xla(float x) {
  float w = -log1pf(-x * x);
  float p;
  if (w < 5.0f) {
    w -= 2.5f;
    p = 2.81022636e-08f;
    p = fmaf(p, w, 3.43273939e-07f);
    p = fmaf(p, w, -3.5233877e-06f);
    p = fmaf(p, w, -4.39150654e-06f);
    p = fmaf(p, w, 0.00021858087f);
    p = fmaf(p, w, -0.00125372503f);
    p = fmaf(p, w, -0.00417768164f);
    p = fmaf(p, w, 0.246640727f);
    p = fmaf(p, w, 1.50140941f);
  } else {
    w = sqrtf(w) - 3.0f;
    p = -0.000200214257f;
    p = fmaf(p, w, 0.000100950558f);
    p = fmaf(p, w, 0.00134934322f);
    p = fmaf(p, w, -0.00367342844f);
    p = fmaf(p, w, 0.00573950773f);
    p = fmaf(p, w, -0.0076224613f);
    p = fmaf(p, w, 0.00943887047f);
    p = fmaf(p, w, 1.00167406f);
    p = fmaf(p, w, 2.83297682f);
  }
  return p * x;
}

// Fast exact-style GELU: erf via Abramowitz-Stegun 7.1.26 (|err|<=1.5e-7,
// far below bf16 eps). ~14 VALU vs ~35+ for libm erff.
__device__ __forceinline__ float gelu_fast(float x) {
  float z  = x * 0.7071067811865475f;
  float az = fabsf(z);
  float t  = __builtin_amdgcn_rcpf(fmaf(0.3275911f, az, 1.0f));
  float p  = fmaf(1.061405429f, t, -1.453152027f);
  p = fmaf(p, t, 1.421413741f);
  p = fmaf(p, t, -0.284496736f);
  p = fmaf(p, t, 0.254829592f);
  p *= t;
  float e  = exp2f(az * az * -1.4426950408889634f);
  float er = fmaf(-p, e, 1.0f);
  er = copysignf(er, z);
  return 0.5f * x * (1.0f + er);
}

// MFMA 16x16x32 bf16 micro-GEMM: M=16 (one tile), N=NT*16, K=KSTEPS*32.
// A in LDS (base already offset to this wave's mtile), B in global [N][K].
template<int KSTEPS, int NT, int ASTRIDE, int BSTRIDE>
__device__ __forceinline__ void gemm_w(const bf16* __restrict__ A_lds,
                                       const bf16* __restrict__ B_gbl,
                                       int lane, floatx4 (&acc)[NT]) {
  const int m = lane & 15, q = lane >> 4;
  const bf16* a0 = A_lds + m * ASTRIDE + q * 8;
  const bf16* b0 = B_gbl + m * BSTRIDE + q * 8;
#pragma unroll
  for (int ks = 0; ks < KSTEPS; ++ks) {
    bf16x8 af = *(const bf16x8*)(a0 + ks * 32);
#pragma unroll
    for (int nt = 0; nt < NT; ++nt) {
      bf16x8 bfr = *(const bf16x8*)(b0 + nt * 16 * BSTRIDE + ks * 32);
      acc[nt] = __builtin_amdgcn_mfma_f32_16x16x32_bf16(af, bfr, acc[nt], 0, 0, 0);
    }
  }
}

// ---------------------------------------------------------------------------
// Prep: bf16-transpose weights [N][K]; per-step L1 bias; step consts; keys.
// ---------------------------------------------------------------------------
__global__ void diff_prep(const float* __restrict__ W1, const float* __restrict__ b1,
                          const float* __restrict__ W2, const float* __restrict__ W3,
                          const float* __restrict__ W4, const int* __restrict__ tsurv,
                          bf16* __restrict__ w1t, bf16* __restrict__ w2t,
                          bf16* __restrict__ w3t, bf16* __restrict__ w4t,
                          float* __restrict__ eb1, uint32_t* __restrict__ fk,
                          float* __restrict__ cst) {
  const int tid = blockIdx.x * blockDim.x + threadIdx.x;
  const int nth = gridDim.x * blockDim.x;
  for (int i = tid; i < 512 * 256; i += nth) {
    int n = i >> 8, k = i & 255;
    w1t[i] = (bf16)W1[k * 512 + n];
  }
  for (int i = tid; i < 512 * 512; i += nth) {
    int n = i >> 9, k = i & 511;
    w2t[i] = (bf16)W2[k * 512 + n];
    w3t[i] = (bf16)W3[k * 512 + n];
  }
  for (int i = tid; i < 128 * 512; i += nth) {
    int n = i >> 9, k = i & 511;
    w4t[i] = (bf16)W4[k * 128 + n];
  }
  const float tgt = (tsurv[0] != 0) ? 0.0f : 1.0f;
  for (int i = tid; i < NSTEPS * 512; i += nth) {
    int t = i >> 9, n = i & 511;
    eb1[i] = b1[n] + ((float)t / 50.0f) * W1[256 * 512 + n] + tgt * W1[257 * 512 + n];
  }
  if (tid == 0) {
    float ac = 1.0f;
    for (int t = 0; t < NSTEPS; ++t) {
      float beta  = 1e-4f + (0.02f - 1e-4f) * ((float)t / 49.0f);
      float alpha = 1.0f - beta;
      ac *= alpha;
      cst[t]            = beta / sqrtf(1.0f - ac);
      cst[NSTEPS + t]   = 1.0f / sqrtf(alpha);
      cst[2*NSTEPS + t] = sqrtf(beta);
      uint32_t o0, o1;
      threefry2x32(0u, 42u, 0u, (uint32_t)t, o0, o1);  // fold_in(key(42), t)
      fk[t] = o0; fk[NSTEPS + t] = o1;
    }
  }
}

// ---------------------------------------------------------------------------
// Main persistent kernel: 256 WGs x 1024 threads. LDS 41KB (xb + single hb).
// 6 barriers/step. x-state f32 lives in 4 regs/lane (ownership fixed).
// ---------------------------------------------------------------------------
__global__ __launch_bounds__(1024, 4) void diff_main(
    const float* __restrict__ cond, const float* __restrict__ xinit,
    const bf16* __restrict__ w1t, const bf16* __restrict__ w2t,
    const bf16* __restrict__ w3t, const bf16* __restrict__ w4t,
    const float* __restrict__ eb1, const float* __restrict__ b2,
    const float* __restrict__ b3, const float* __restrict__ b4,
    const uint32_t* __restrict__ fk, const float* __restrict__ cst,
    float* __restrict__ out) {
  __shared__ bf16 xb[WG_ROWS * XB_STRIDE];   // x as bf16 (layer-1 A operand)
  __shared__ bf16 hb[WG_ROWS * H_STRIDE];    // hidden buffer (h1/h2/h3)

  const int tid   = threadIdx.x;
  const int wave  = tid >> 6;
  const int lane  = tid & 63;
  const int m     = lane & 15, q = lane >> 4;
  const int mtile = wave >> 3;               // 0..1 (row half)
  const int ntile = wave & 7;                // 0..7 (64-col slice for 512-wide)
  const int r0    = blockIdx.x * WG_ROWS;

  const bf16* A_my = hb + mtile * 16 * H_STRIDE;
  const bf16* X_my = xb + mtile * 16 * XB_STRIDE;

  // x-state ownership (fixed across steps): rows mtile*16+q*4+r, col (w&7)*16+m
  const int xcol = ntile * 16 + m;
  const int xrow0 = mtile * 16 + q * 4;

  // ---- init: stage x_init(bf16)->xb, cond(bf16)->hb, x-state->regs ----
  {
    const int row = tid >> 5;
    const int c4  = (tid & 31) * 4;
    float4 a = *(const float4*)(xinit + (size_t)(r0 + row) * 128 + c4);
    float4 c = *(const float4*)(cond  + (size_t)(r0 + row) * 128 + c4);
    bf16x4 x4, c4v;
    x4[0] = (bf16)a.x; x4[1] = (bf16)a.y; x4[2] = (bf16)a.z; x4[3] = (bf16)a.w;
    c4v[0] = (bf16)c.x; c4v[1] = (bf16)c.y; c4v[2] = (bf16)c.z; c4v[3] = (bf16)c.w;
    *(bf16x4*)(xb + row * XB_STRIDE + c4) = x4;
    *(bf16x4*)(hb + row * H_STRIDE  + c4) = c4v;
  }
  float xreg[4];
#pragma unroll
  for (int r = 0; r < 4; ++r)
    xreg[r] = xinit[(size_t)(r0 + xrow0 + r) * 128 + xcol];
  __syncthreads();

  // ---- cproj = cond @ W1[128:256,:] (same acc layout layer 1 will use) ----
  floatx4 cpr[4] = {};
  gemm_w<4, 4, H_STRIDE, 256>(A_my, w1t + (ntile * 64) * 256 + 128, lane, cpr);
  __syncthreads();  // cond reads done; hb free for h1

  for (int t = NSTEPS - 1; t >= 0; --t) {
    // ---- layer 1: h1 = gelu(x@W1[:128] + cproj + eb1[t]) ----
    // (reads xb only — no pre-write barrier needed on hb: all hb readers
    //  of the previous step finished before the end-of-step barrier)
    {
      floatx4 acc[4] = {};
      gemm_w<4, 4, XB_STRIDE, 256>(X_my, w1t + (ntile * 64) * 256, lane, acc);
      const float* ebt = eb1 + t * 512;
#pragma unroll
      for (int nt = 0; nt < 4; ++nt) {
        const int col = ntile * 64 + nt * 16 + m;
        const float bb = ebt[col];
#pragma unroll
        for (int r = 0; r < 4; ++r) {
          const int row = mtile * 16 + q * 4 + r;
          hb[row * H_STRIDE + col] = (bf16)gelu_fast(acc[nt][r] + cpr[nt][r] + bb);
        }
      }
    }
    __syncthreads();

    // ---- layer 2: h2 = gelu(h1@W2 + b2) ----
    {
      floatx4 acc[4] = {};
      gemm_w<16, 4, H_STRIDE, 512>(A_my, w2t + (ntile * 64) * 512, lane, acc);
      __syncthreads();  // all h1 reads done before overwrite
#pragma unroll
      for (int nt = 0; nt < 4; ++nt) {
        const int col = ntile * 64 + nt * 16 + m;
        const float bb = b2[col];
#pragma unroll
        for (int r = 0; r < 4; ++r) {
          const int row = mtile * 16 + q * 4 + r;
          hb[row * H_STRIDE + col] = (bf16)gelu_fast(acc[nt][r] + bb);
        }
      }
    }
    __syncthreads();

    // ---- layer 3: h3 = gelu(h2@W3 + b3) ----
    {
      floatx4 acc[4] = {};
      gemm_w<16, 4, H_STRIDE, 512>(A_my, w3t + (ntile * 64) * 512, lane, acc);
      __syncthreads();
#pragma unroll
      for (int nt = 0; nt < 4; ++nt) {
        const int col = ntile * 64 + nt * 16 + m;
        const float bb = b3[col];
#pragma unroll
        for (int r = 0; r < 4; ++r) {
          const int row = mtile * 16 + q * 4 + r;
          hb[row * H_STRIDE + col] = (bf16)gelu_fast(acc[nt][r] + bb);
        }
      }
    }
    __syncthreads();

    // ---- layer 4 + DDPM update: wave owns 16 cols x its 16-row half ----
    {
      floatx4 acc[1] = {};
      gemm_w<16, 1, H_STRIDE, 512>(A_my, w4t + (ntile * 16) * 512, lane, acc);
      const float c1 = cst[t], c2 = cst[NSTEPS + t], c3 = cst[2 * NSTEPS + t];
      const uint32_t fk0 = fk[t], fk1 = fk[NSTEPS + t];
      const float bb = b4[xcol];
#pragma unroll
      for (int r = 0; r < 4; ++r) {
        const int row = xrow0 + r;
        float np = acc[0][r] + bb;
        float z = 0.0f;
        if (t > 0) {
          // JAX partitionable random_bits: bits = o0 ^ o1, x1 = flat index
          uint32_t gidx = (uint32_t)(r0 + row) * 128u + (uint32_t)xcol;
          uint32_t o0, o1;
          threefry2x32(fk0, fk1, 0u, gidx, o0, o1);
          uint32_t bits = o0 ^ o1;
          float f01 = __uint_as_float((bits >> 9) | 0x3F800000u) - 1.0f;
          float u = f01 * 2.0f + (-0.99999994f);
          u = fmaxf(-0.99999994f, u);
          z = 1.4142135381698608f * erfinv_xla(u);
        }
        float xn = (xreg[r] - c1 * np) * c2 + c3 * z;
        xreg[r] = xn;
        xb[row * XB_STRIDE + xcol] = (bf16)xn;
      }
    }
    __syncthreads();  // xb ready for next step's layer 1; hb reads drained
  }

  // ---- writeout from registers ----
#pragma unroll
  for (int r = 0; r < 4; ++r)
    out[(size_t)(r0 + xrow0 + r) * 128 + xcol] = xreg[r];
}

// ---------------------------------------------------------------------------
extern "C" void kernel_launch(void* const* d_in, const int* in_sizes, int n_in,
                              void* d_out, int out_size, void* d_ws, size_t ws_size,
                              hipStream_t stream) {
  const float* cond  = (const float*)d_in[0];
  const float* xinit = (const float*)d_in[1];
  const float* W1 = (const float*)d_in[2];
  const float* b1 = (const float*)d_in[3];
  const float* W2 = (const float*)d_in[4];
  const float* b2 = (const float*)d_in[5];
  const float* W3 = (const float*)d_in[6];
  const float* b3 = (const float*)d_in[7];
  const float* W4 = (const float*)d_in[8];
  const float* b4 = (const float*)d_in[9];
  const int* tsurv = (const int*)d_in[10];

  char* ws = (char*)d_ws;
  bf16* w1t = (bf16*)(ws + 0);               // 512*256*2 = 262144
  bf16* w2t = (bf16*)(ws + 262144);          // 512*512*2 = 524288
  bf16* w3t = (bf16*)(ws + 786432);          // 524288
  bf16* w4t = (bf16*)(ws + 1310720);         // 128*512*2 = 131072
  float* eb1 = (float*)(ws + 1441792);       // 50*512*4 = 102400
  uint32_t* fkp = (uint32_t*)(ws + 1544192); // 100*4
  float* cstp = (float*)(ws + 1544704);      // 150*4

  diff_prep<<<1024, 256, 0, stream>>>(W1, b1, W2, W3, W4, tsurv,
                                      w1t, w2t, w3t, w4t, eb1, fkp, cstp);
  diff_main<<<256, 1024, 0, stream>>>(cond, xinit, w1t, w2t, w3t, w4t,
                                      eb1, b2, b3, b4, fkp, cstp, (float*)d_out);
}

// Round 4
// 2618.450 us; speedup vs baseline: 2.5756x; 2.5756x over previous
//
#include <hip/hip_runtime.h>
#include <stdint.h>
#include <stddef.h>

// ---------------------------------------------------------------------------
// CounterfactualDiffusion: 50 sequential steps of 4-layer MLP (258->512->512
// ->512->128) + DDPM update with JAX partitionable-threefry noise, batch 8192.
// Persistent kernel: 256 WGs x 1024 threads (16 waves = 4/SIMD), each WG owns
// 32 rows for all 50 steps. Weights stream from L2 (1.44MB bf16 distinct per
// WG-step, each line requested ONCE: waves own disjoint 32-col B slices and
// reuse one B-fragment for both 16-row A tiles — the R2 pattern that kept
// FETCH_SIZE at ~10MB). K-loops use shallow unroll(2) so loads pipeline
// without blowing the VGPR budget (R3's full unroll serialized on vmcnt).
// ---------------------------------------------------------------------------

typedef __bf16 bf16;
typedef __bf16 bf16x4 __attribute__((ext_vector_type(4)));
typedef __bf16 bf16x8 __attribute__((ext_vector_type(8)));
typedef float  floatx4 __attribute__((ext_vector_type(4)));

#define NSTEPS    50
#define WG_ROWS   32
#define XB_STRIDE 136   // 128 + 8 pad (16B-aligned rows)
#define H_STRIDE  520   // 512 + 8 pad

__device__ __forceinline__ uint32_t rotl32(uint32_t x, int r) {
  return (x << r) | (x >> (32 - r));
}

// JAX threefry-2x32, 20 rounds.
__device__ __forceinline__ void threefry2x32(uint32_t k0, uint32_t k1,
                                             uint32_t x0, uint32_t x1,
                                             uint32_t& o0, uint32_t& o1) {
  uint32_t k2 = k0 ^ k1 ^ 0x1BD11BDAu;
  x0 += k0; x1 += k1;
#define TF_R(R) { x0 += x1; x1 = rotl32(x1, R); x1 ^= x0; }
  TF_R(13) TF_R(15) TF_R(26) TF_R(6)
  x0 += k1; x1 += k2 + 1u;
  TF_R(17) TF_R(29) TF_R(16) TF_R(24)
  x0 += k2; x1 += k0 + 2u;
  TF_R(13) TF_R(15) TF_R(26) TF_R(6)
  x0 += k0; x1 += k1 + 3u;
  TF_R(17) TF_R(29) TF_R(16) TF_R(24)
  x0 += k1; x1 += k2 + 4u;
  TF_R(13) TF_R(15) TF_R(26) TF_R(6)
  x0 += k2; x1 += k0 + 5u;
#undef TF_R
  o0 = x0; o1 = x1;
}

// XLA's ErfInv32 (Giles) — matches lax.erf_inv f32 path.
__device__ __forceinline__ float erfinv_xla(float x) {
  float w = -log1pf(-x * x);
  float p;
  if (w < 5.0f) {
    w -= 2.5f;
    p = 2.81022636e-08f;
    p = fmaf(p, w, 3.43273939e-07f);
    p = fmaf(p, w, -3.5233877e-06f);
    p = fmaf(p, w, -4.39150654e-06f);
    p = fmaf(p, w, 0.00021858087f);
    p = fmaf(p, w, -0.00125372503f);
    p = fmaf(p, w, -0.00417768164f);
    p = fmaf(p, w, 0.246640727f);
    p = fmaf(p, w, 1.50140941f);
  } else {
    w = sqrtf(w) - 3.0f;
    p = -0.000200214257f;
    p = fmaf(p, w, 0.000100950558f);
    p = fmaf(p, w, 0.00134934322f);
    p = fmaf(p, w, -0.00367342844f);
    p = fmaf(p, w, 0.00573950773f);
    p = fmaf(p, w, -0.0076224613f);
    p = fmaf(p, w, 0.00943887047f);
    p = fmaf(p, w, 1.00167406f);
    p = fmaf(p, w, 2.83297682f);
  }
  return p * x;
}

// Fast GELU: erf via Abramowitz-Stegun 7.1.26 (|err|<=1.5e-7 << bf16 eps).
__device__ __forceinline__ float gelu_fast(float x) {
  float z  = x * 0.7071067811865475f;
  float az = fabsf(z);
  float t  = __builtin_amdgcn_rcpf(fmaf(0.3275911f, az, 1.0f));
  float p  = fmaf(1.061405429f, t, -1.453152027f);
  p = fmaf(p, t, 1.421413741f);
  p = fmaf(p, t, -0.284496736f);
  p = fmaf(p, t, 0.254829592f);
  p *= t;
  float e  = exp2f(az * az * -1.4426950408889634f);
  float er = fmaf(-p, e, 1.0f);
  er = copysignf(er, z);
  return 0.5f * x * (1.0f + er);
}

// MFMA 16x16x32 bf16 micro-GEMM, M=32 (2 row-tiles SHARING each B-fragment),
// N = NT*16, K = KSTEPS*32. A in LDS, B in global [N][K] pre-transposed.
template<int KSTEPS, int NT, int ASTRIDE, int BSTRIDE>
__device__ __forceinline__ void gemm2(const bf16* __restrict__ A_lds,
                                      const bf16* __restrict__ B_gbl,
                                      int lane, floatx4 (&acc)[2][NT]) {
  const int m = lane & 15, q = lane >> 4;
  const bf16* a0 = A_lds + m * ASTRIDE + q * 8;
  const bf16* b0 = B_gbl + m * BSTRIDE + q * 8;
#pragma unroll 2
  for (int ks = 0; ks < KSTEPS; ++ks) {
    bf16x8 af0 = *(const bf16x8*)(a0 + ks * 32);
    bf16x8 af1 = *(const bf16x8*)(a0 + 16 * ASTRIDE + ks * 32);
#pragma unroll
    for (int nt = 0; nt < NT; ++nt) {
      bf16x8 bfr = *(const bf16x8*)(b0 + nt * 16 * BSTRIDE + ks * 32);
      acc[0][nt] = __builtin_amdgcn_mfma_f32_16x16x32_bf16(af0, bfr, acc[0][nt], 0, 0, 0);
      acc[1][nt] = __builtin_amdgcn_mfma_f32_16x16x32_bf16(af1, bfr, acc[1][nt], 0, 0, 0);
    }
  }
}

// Single row-tile variant for layer 4 (M=16, N=16).
template<int KSTEPS, int ASTRIDE, int BSTRIDE>
__device__ __forceinline__ void gemm1(const bf16* __restrict__ A_lds,
                                      const bf16* __restrict__ B_gbl,
                                      int lane, floatx4& acc) {
  const int m = lane & 15, q = lane >> 4;
  const bf16* a0 = A_lds + m * ASTRIDE + q * 8;
  const bf16* b0 = B_gbl + m * BSTRIDE + q * 8;
#pragma unroll 2
  for (int ks = 0; ks < KSTEPS; ++ks) {
    bf16x8 af  = *(const bf16x8*)(a0 + ks * 32);
    bf16x8 bfr = *(const bf16x8*)(b0 + ks * 32);
    acc = __builtin_amdgcn_mfma_f32_16x16x32_bf16(af, bfr, acc, 0, 0, 0);
  }
}

// ---------------------------------------------------------------------------
// Prep: bf16-transpose weights [N][K]; per-step L1 bias; step consts; keys.
// ---------------------------------------------------------------------------
__global__ void diff_prep(const float* __restrict__ W1, const float* __restrict__ b1,
                          const float* __restrict__ W2, const float* __restrict__ W3,
                          const float* __restrict__ W4, const int* __restrict__ tsurv,
                          bf16* __restrict__ w1t, bf16* __restrict__ w2t,
                          bf16* __restrict__ w3t, bf16* __restrict__ w4t,
                          float* __restrict__ eb1, uint32_t* __restrict__ fk,
                          float* __restrict__ cst) {
  const int tid = blockIdx.x * blockDim.x + threadIdx.x;
  const int nth = gridDim.x * blockDim.x;
  for (int i = tid; i < 512 * 256; i += nth) {
    int n = i >> 8, k = i & 255;
    w1t[i] = (bf16)W1[k * 512 + n];
  }
  for (int i = tid; i < 512 * 512; i += nth) {
    int n = i >> 9, k = i & 511;
    w2t[i] = (bf16)W2[k * 512 + n];
    w3t[i] = (bf16)W3[k * 512 + n];
  }
  for (int i = tid; i < 128 * 512; i += nth) {
    int n = i >> 9, k = i & 511;
    w4t[i] = (bf16)W4[k * 128 + n];
  }
  const float tgt = (tsurv[0] != 0) ? 0.0f : 1.0f;
  for (int i = tid; i < NSTEPS * 512; i += nth) {
    int t = i >> 9, n = i & 511;
    eb1[i] = b1[n] + ((float)t / 50.0f) * W1[256 * 512 + n] + tgt * W1[257 * 512 + n];
  }
  if (tid == 0) {
    float ac = 1.0f;
    for (int t = 0; t < NSTEPS; ++t) {
      float beta  = 1e-4f + (0.02f - 1e-4f) * ((float)t / 49.0f);
      float alpha = 1.0f - beta;
      ac *= alpha;
      cst[t]            = beta / sqrtf(1.0f - ac);
      cst[NSTEPS + t]   = 1.0f / sqrtf(alpha);
      cst[2*NSTEPS + t] = sqrtf(beta);
      uint32_t o0, o1;
      threefry2x32(0u, 42u, 0u, (uint32_t)t, o0, o1);  // fold_in(key(42), t)
      fk[t] = o0; fk[NSTEPS + t] = o1;
    }
  }
}

// ---------------------------------------------------------------------------
// Main persistent kernel: 256 WGs x 1024 threads, 16 waves.
// Layers 1-3: wave w owns cols [w*32, w*32+32) (disjoint B slices).
// Layer 4 + update: mtile = w>>3, ntile = w&7 (16 waves cover 2x8 tiles).
// LDS 42KB (xb + single hb). 6 barriers/step. x-state f32 in 4 regs/lane.
// ---------------------------------------------------------------------------
__global__ __launch_bounds__(1024, 4) void diff_main(
    const float* __restrict__ cond, const float* __restrict__ xinit,
    const bf16* __restrict__ w1t, const bf16* __restrict__ w2t,
    const bf16* __restrict__ w3t, const bf16* __restrict__ w4t,
    const float* __restrict__ eb1, const float* __restrict__ b2,
    const float* __restrict__ b3, const float* __restrict__ b4,
    const uint32_t* __restrict__ fk, const float* __restrict__ cst,
    float* __restrict__ out) {
  __shared__ bf16 xb[WG_ROWS * XB_STRIDE];   // x as bf16 (layer-1 A operand)
  __shared__ bf16 hb[WG_ROWS * H_STRIDE];    // hidden buffer (h1/h2/h3)

  const int tid  = threadIdx.x;
  const int wave = tid >> 6;
  const int lane = tid & 63;
  const int m    = lane & 15, q = lane >> 4;
  const int r0   = blockIdx.x * WG_ROWS;
  const int c0   = wave * 32;                // this wave's col slice (layers 1-3)

  // layer-4 / x-state ownership: rows (w>>3)*16+q*4..+4, col (w&7)*16+m
  const int mtile4 = wave >> 3;
  const int ntile4 = wave & 7;
  const int xcol  = ntile4 * 16 + m;
  const int xrow0 = mtile4 * 16 + q * 4;

  // ---- init: stage x_init(bf16)->xb, cond(bf16)->hb, x-state->regs ----
  {
    const int row = tid >> 5;
    const int c4  = (tid & 31) * 4;
    float4 a = *(const float4*)(xinit + (size_t)(r0 + row) * 128 + c4);
    float4 c = *(const float4*)(cond  + (size_t)(r0 + row) * 128 + c4);
    bf16x4 x4, c4v;
    x4[0] = (bf16)a.x; x4[1] = (bf16)a.y; x4[2] = (bf16)a.z; x4[3] = (bf16)a.w;
    c4v[0] = (bf16)c.x; c4v[1] = (bf16)c.y; c4v[2] = (bf16)c.z; c4v[3] = (bf16)c.w;
    *(bf16x4*)(xb + row * XB_STRIDE + c4) = x4;
    *(bf16x4*)(hb + row * H_STRIDE  + c4) = c4v;
  }
  float xreg[4];
#pragma unroll
  for (int r = 0; r < 4; ++r)
    xreg[r] = xinit[(size_t)(r0 + xrow0 + r) * 128 + xcol];
  __syncthreads();

  // ---- cproj = cond @ W1[128:256,:] (acc layout matches layer 1) ----
  floatx4 cpr[2][2] = {};
  gemm2<4, 2, H_STRIDE, 256>(hb, w1t + c0 * 256 + 128, lane, cpr);
  __syncthreads();  // cond reads done; hb free for h1

  for (int t = NSTEPS - 1; t >= 0; --t) {
    // ---- layer 1: h1 = gelu(x@W1[:128] + cproj + eb1[t]) (reads xb only) ----
    {
      floatx4 acc[2][2] = {};
      gemm2<4, 2, XB_STRIDE, 256>(xb, w1t + c0 * 256, lane, acc);
      const float* ebt = eb1 + t * 512;
#pragma unroll
      for (int nt = 0; nt < 2; ++nt) {
        const int col = c0 + nt * 16 + m;
        const float bb = ebt[col];
#pragma unroll
        for (int mt = 0; mt < 2; ++mt)
#pragma unroll
          for (int r = 0; r < 4; ++r) {
            const int row = mt * 16 + q * 4 + r;
            hb[row * H_STRIDE + col] = (bf16)gelu_fast(acc[mt][nt][r] + cpr[mt][nt][r] + bb);
          }
      }
    }
    __syncthreads();

    // ---- layer 2: h2 = gelu(h1@W2 + b2) ----
    {
      floatx4 acc[2][2] = {};
      gemm2<16, 2, H_STRIDE, 512>(hb, w2t + c0 * 512, lane, acc);
      __syncthreads();  // all h1 reads done before overwrite
#pragma unroll
      for (int nt = 0; nt < 2; ++nt) {
        const int col = c0 + nt * 16 + m;
        const float bb = b2[col];
#pragma unroll
        for (int mt = 0; mt < 2; ++mt)
#pragma unroll
          for (int r = 0; r < 4; ++r) {
            const int row = mt * 16 + q * 4 + r;
            hb[row * H_STRIDE + col] = (bf16)gelu_fast(acc[mt][nt][r] + bb);
          }
      }
    }
    __syncthreads();

    // ---- layer 3: h3 = gelu(h2@W3 + b3) ----
    {
      floatx4 acc[2][2] = {};
      gemm2<16, 2, H_STRIDE, 512>(hb, w3t + c0 * 512, lane, acc);
      __syncthreads();
#pragma unroll
      for (int nt = 0; nt < 2; ++nt) {
        const int col = c0 + nt * 16 + m;
        const float bb = b3[col];
#pragma unroll
        for (int mt = 0; mt < 2; ++mt)
#pragma unroll
          for (int r = 0; r < 4; ++r) {
            const int row = mt * 16 + q * 4 + r;
            hb[row * H_STRIDE + col] = (bf16)gelu_fast(acc[mt][nt][r] + bb);
          }
      }
    }
    __syncthreads();

    // ---- layer 4 + DDPM update: wave owns 16 cols x 16-row half ----
    {
      floatx4 acc = {};
      gemm1<16, H_STRIDE, 512>(hb + mtile4 * 16 * H_STRIDE,
                               w4t + (ntile4 * 16) * 512, lane, acc);
      const float c1 = cst[t], c2 = cst[NSTEPS + t], c3 = cst[2 * NSTEPS + t];
      const uint32_t fk0 = fk[t], fk1 = fk[NSTEPS + t];
      const float bb = b4[xcol];
#pragma unroll
      for (int r = 0; r < 4; ++r) {
        const int row = xrow0 + r;
        float np = acc[r] + bb;
        float z = 0.0f;
        if (t > 0) {
          // JAX partitionable random_bits: bits = o0 ^ o1, x1 = flat index
          uint32_t gidx = (uint32_t)(r0 + row) * 128u + (uint32_t)xcol;
          uint32_t o0, o1;
          threefry2x32(fk0, fk1, 0u, gidx, o0, o1);
          uint32_t bits = o0 ^ o1;
          float f01 = __uint_as_float((bits >> 9) | 0x3F800000u) - 1.0f;
          float u = f01 * 2.0f + (-0.99999994f);
          u = fmaxf(-0.99999994f, u);
          z = 1.4142135381698608f * erfinv_xla(u);
        }
        float xn = (xreg[r] - c1 * np) * c2 + c3 * z;
        xreg[r] = xn;
        xb[row * XB_STRIDE + xcol] = (bf16)xn;
      }
    }
    __syncthreads();  // xb ready for next step; hb reads drained
  }

  // ---- writeout from registers ----
#pragma unroll
  for (int r = 0; r < 4; ++r)
    out[(size_t)(r0 + xrow0 + r) * 128 + xcol] = xreg[r];
}

// ---------------------------------------------------------------------------
extern "C" void kernel_launch(void* const* d_in, const int* in_sizes, int n_in,
                              void* d_out, int out_size, void* d_ws, size_t ws_size,
                              hipStream_t stream) {
  const float* cond  = (const float*)d_in[0];
  const float* xinit = (const float*)d_in[1];
  const float* W1 = (const float*)d_in[2];
  const float* b1 = (const float*)d_in[3];
  const float* W2 = (const float*)d_in[4];
  const float* b2 = (const float*)d_in[5];
  const float* W3 = (const float*)d_in[6];
  const float* b3 = (const float*)d_in[7];
  const float* W4 = (const float*)d_in[8];
  const float* b4 = (const float*)d_in[9];
  const int* tsurv = (const int*)d_in[10];

  char* ws = (char*)d_ws;
  bf16* w1t = (bf16*)(ws + 0);               // 512*256*2 = 262144
  bf16* w2t = (bf16*)(ws + 262144);          // 512*512*2 = 524288
  bf16* w3t = (bf16*)(ws + 786432);          // 524288
  bf16* w4t = (bf16*)(ws + 1310720);         // 128*512*2 = 131072
  float* eb1 = (float*)(ws + 1441792);       // 50*512*4 = 102400
  uint32_t* fkp = (uint32_t*)(ws + 1544192); // 100*4
  float* cstp = (float*)(ws + 1544704);      // 150*4

  diff_prep<<<1024, 256, 0, stream>>>(W1, b1, W2, W3, W4, tsurv,
                                      w1t, w2t, w3t, w4t, eb1, fkp, cstp);
  diff_main<<<256, 1024, 0, stream>>>(cond, xinit, w1t, w2t, w3t, w4t,
                                      eb1, b2, b3, b4, fkp, cstp, (float*)d_out);
}

// Round 5
// 1256.037 us; speedup vs baseline: 5.3694x; 2.0847x over previous
//
#include <hip/hip_runtime.h>
#include <stdint.h>
#include <stddef.h>

// ---------------------------------------------------------------------------
// CounterfactualDiffusion: 50 sequential steps of 4-layer MLP (258->512->512
// ->512->128) + DDPM update with JAX partitionable-threefry noise, batch 8192.
// Persistent kernel: 256 WGs x 1024 threads (16 waves), each WG owns 32 rows
// for all 50 steps. Weights pre-packed in MFMA-FRAGMENT ORDER so every
// B-operand load is a wave-contiguous 1KB burst (R4's [N][K] layout made each
// load hit 16 scattered 64B segments -> TA-serialized; R2==R4 runtime showed
// the per-CU vmem front-end was the wall, not wave count).
// Double-buffered hb (hbA/hbB) cuts barriers 6 -> 4 per step.
// ---------------------------------------------------------------------------

typedef __bf16 bf16;
typedef __bf16 bf16x4 __attribute__((ext_vector_type(4)));
typedef __bf16 bf16x8 __attribute__((ext_vector_type(8)));
typedef float  floatx4 __attribute__((ext_vector_type(4)));

#define NSTEPS    50
#define WG_ROWS   32
#define XB_STRIDE 136   // 128 + 8 pad
#define H_STRIDE  520   // 512 + 8 pad

__device__ __forceinline__ uint32_t rotl32(uint32_t x, int r) {
  return (x << r) | (x >> (32 - r));
}

// JAX threefry-2x32, 20 rounds.
__device__ __forceinline__ void threefry2x32(uint32_t k0, uint32_t k1,
                                             uint32_t x0, uint32_t x1,
                                             uint32_t& o0, uint32_t& o1) {
  uint32_t k2 = k0 ^ k1 ^ 0x1BD11BDAu;
  x0 += k0; x1 += k1;
#define TF_R(R) { x0 += x1; x1 = rotl32(x1, R); x1 ^= x0; }
  TF_R(13) TF_R(15) TF_R(26) TF_R(6)
  x0 += k1; x1 += k2 + 1u;
  TF_R(17) TF_R(29) TF_R(16) TF_R(24)
  x0 += k2; x1 += k0 + 2u;
  TF_R(13) TF_R(15) TF_R(26) TF_R(6)
  x0 += k0; x1 += k1 + 3u;
  TF_R(17) TF_R(29) TF_R(16) TF_R(24)
  x0 += k1; x1 += k2 + 4u;
  TF_R(13) TF_R(15) TF_R(26) TF_R(6)
  x0 += k2; x1 += k0 + 5u;
#undef TF_R
  o0 = x0; o1 = x1;
}

// XLA's ErfInv32 (Giles) — matches lax.erf_inv f32 path.
__device__ __forceinline__ float erfinv_xla(float x) {
  float w = -log1pf(-x * x);
  float p;
  if (w < 5.0f) {
    w -= 2.5f;
    p = 2.81022636e-08f;
    p = fmaf(p, w, 3.43273939e-07f);
    p = fmaf(p, w, -3.5233877e-06f);
    p = fmaf(p, w, -4.39150654e-06f);
    p = fmaf(p, w, 0.00021858087f);
    p = fmaf(p, w, -0.00125372503f);
    p = fmaf(p, w, -0.00417768164f);
    p = fmaf(p, w, 0.246640727f);
    p = fmaf(p, w, 1.50140941f);
  } else {
    w = sqrtf(w) - 3.0f;
    p = -0.000200214257f;
    p = fmaf(p, w, 0.000100950558f);
    p = fmaf(p, w, 0.00134934322f);
    p = fmaf(p, w, -0.00367342844f);
    p = fmaf(p, w, 0.00573950773f);
    p = fmaf(p, w, -0.0076224613f);
    p = fmaf(p, w, 0.00943887047f);
    p = fmaf(p, w, 1.00167406f);
    p = fmaf(p, w, 2.83297682f);
  }
  return p * x;
}

// Fast GELU: erf via Abramowitz-Stegun 7.1.26 (|err|<=1.5e-7 << bf16 eps).
__device__ __forceinline__ float gelu_fast(float x) {
  float z  = x * 0.7071067811865475f;
  float az = fabsf(z);
  float t  = __builtin_amdgcn_rcpf(fmaf(0.3275911f, az, 1.0f));
  float p  = fmaf(1.061405429f, t, -1.453152027f);
  p = fmaf(p, t, 1.421413741f);
  p = fmaf(p, t, -0.284496736f);
  p = fmaf(p, t, 0.254829592f);
  p *= t;
  float e  = exp2f(az * az * -1.4426950408889634f);
  float er = fmaf(-p, e, 1.0f);
  er = copysignf(er, z);
  return 0.5f * x * (1.0f + er);
}

// MFMA 16x16x32 bf16 micro-GEMM, M=32 (2 row-tiles sharing each B-fragment),
// N = NT*16, K = KSTEPS*32. A in LDS row-major; B pre-packed fragment-order:
// element (ntile, ks, lane, j) at Bp[((ntile*KSTEPS + ks)*64 + lane)*8 + j]
// -> each wave load is 64 lanes x 16B = 1KB CONTIGUOUS.
template<int KSTEPS, int NT, int ASTRIDE, int UNROLL>
__device__ __forceinline__ void gemm2(const bf16* __restrict__ A_lds,
                                      const bf16* __restrict__ B_pk,
                                      int lane, floatx4 (&acc)[2][NT]) {
  const int m = lane & 15, q = lane >> 4;
  const bf16* a0 = A_lds + m * ASTRIDE + q * 8;
  const bf16* b0 = B_pk + lane * 8;
#pragma unroll UNROLL
  for (int ks = 0; ks < KSTEPS; ++ks) {
    bf16x8 af0 = *(const bf16x8*)(a0 + ks * 32);
    bf16x8 af1 = *(const bf16x8*)(a0 + 16 * ASTRIDE + ks * 32);
#pragma unroll
    for (int nt = 0; nt < NT; ++nt) {
      bf16x8 bfr = *(const bf16x8*)(b0 + (nt * KSTEPS + ks) * 512);
      acc[0][nt] = __builtin_amdgcn_mfma_f32_16x16x32_bf16(af0, bfr, acc[0][nt], 0, 0, 0);
      acc[1][nt] = __builtin_amdgcn_mfma_f32_16x16x32_bf16(af1, bfr, acc[1][nt], 0, 0, 0);
    }
  }
}

// Single row-tile variant for layer 4 (M=16, N=16), packed B.
template<int KSTEPS, int ASTRIDE>
__device__ __forceinline__ void gemm1(const bf16* __restrict__ A_lds,
                                      const bf16* __restrict__ B_pk,
                                      int lane, floatx4& acc) {
  const int m = lane & 15, q = lane >> 4;
  const bf16* a0 = A_lds + m * ASTRIDE + q * 8;
  const bf16* b0 = B_pk + lane * 8;
#pragma unroll 4
  for (int ks = 0; ks < KSTEPS; ++ks) {
    bf16x8 af  = *(const bf16x8*)(a0 + ks * 32);
    bf16x8 bfr = *(const bf16x8*)(b0 + ks * 512);
    acc = __builtin_amdgcn_mfma_f32_16x16x32_bf16(af, bfr, acc, 0, 0, 0);
  }
}

// ---------------------------------------------------------------------------
// Prep: pack weights bf16 in fragment order; per-step L1 bias; consts; keys.
// Fragment index i = ((ntile*KS + ks)*64 + lane)*8 + j maps to
//   n = ntile*16 + (lane&15), k = ks*32 + (lane>>4)*8 + j.
// ---------------------------------------------------------------------------
__global__ void diff_prep(const float* __restrict__ W1, const float* __restrict__ b1,
                          const float* __restrict__ W2, const float* __restrict__ W3,
                          const float* __restrict__ W4, const int* __restrict__ tsurv,
                          bf16* __restrict__ w1p, bf16* __restrict__ w1cp,
                          bf16* __restrict__ w2p, bf16* __restrict__ w3p,
                          bf16* __restrict__ w4p,
                          float* __restrict__ eb1, uint32_t* __restrict__ fk,
                          float* __restrict__ cst) {
  const int tid = blockIdx.x * blockDim.x + threadIdx.x;
  const int nth = gridDim.x * blockDim.x;
  // W1 planes: K=128 each (x-part rows 0..127, cond-part rows 128..255), KS=4
  for (int i = tid; i < 512 * 128; i += nth) {
    int j = i & 7, lane = (i >> 3) & 63, ks = (i >> 9) & 3, ntg = i >> 11;
    int n = ntg * 16 + (lane & 15);
    int k = ks * 32 + (lane >> 4) * 8 + j;
    w1p[i]  = (bf16)W1[k * 512 + n];
    w1cp[i] = (bf16)W1[(128 + k) * 512 + n];
  }
  // W2, W3: K=512, KS=16
  for (int i = tid; i < 512 * 512; i += nth) {
    int j = i & 7, lane = (i >> 3) & 63, ks = (i >> 9) & 15, ntg = i >> 13;
    int n = ntg * 16 + (lane & 15);
    int k = ks * 32 + (lane >> 4) * 8 + j;
    w2p[i] = (bf16)W2[k * 512 + n];
    w3p[i] = (bf16)W3[k * 512 + n];
  }
  // W4: N=128 (8 tiles), K=512, KS=16
  for (int i = tid; i < 128 * 512; i += nth) {
    int j = i & 7, lane = (i >> 3) & 63, ks = (i >> 9) & 15, ntg = i >> 13;
    int n = ntg * 16 + (lane & 15);
    int k = ks * 32 + (lane >> 4) * 8 + j;
    w4p[i] = (bf16)W4[k * 128 + n];
  }
  const float tgt = (tsurv[0] != 0) ? 0.0f : 1.0f;
  for (int i = tid; i < NSTEPS * 512; i += nth) {
    int t = i >> 9, n = i & 511;
    eb1[i] = b1[n] + ((float)t / 50.0f) * W1[256 * 512 + n] + tgt * W1[257 * 512 + n];
  }
  if (tid == 0) {
    float ac = 1.0f;
    for (int t = 0; t < NSTEPS; ++t) {
      float beta  = 1e-4f + (0.02f - 1e-4f) * ((float)t / 49.0f);
      float alpha = 1.0f - beta;
      ac *= alpha;
      cst[t]            = beta / sqrtf(1.0f - ac);
      cst[NSTEPS + t]   = 1.0f / sqrtf(alpha);
      cst[2*NSTEPS + t] = sqrtf(beta);
      uint32_t o0, o1;
      threefry2x32(0u, 42u, 0u, (uint32_t)t, o0, o1);  // fold_in(key(42), t)
      fk[t] = o0; fk[NSTEPS + t] = o1;
    }
  }
}

// ---------------------------------------------------------------------------
// Main persistent kernel: 256 WGs x 1024 threads, 16 waves.
// Layers 1-3: wave w owns cols [w*32, w*32+32). Layer 4: mtile=w>>3, nt=w&7.
// hbA/hbB double-buffer -> 4 barriers/step:
//   L1: xb -> hbA | B1 | L2: hbA -> hbB | B2 | L3: hbB -> hbA | B3 |
//   L4: hbA -> acc; update -> xb | B4
// LDS 73.5KB. x-state f32 in 4 regs/lane.
// ---------------------------------------------------------------------------
__global__ __launch_bounds__(1024, 4) void diff_main(
    const float* __restrict__ cond, const float* __restrict__ xinit,
    const bf16* __restrict__ w1p, const bf16* __restrict__ w1cp,
    const bf16* __restrict__ w2p, const bf16* __restrict__ w3p,
    const bf16* __restrict__ w4p,
    const float* __restrict__ eb1, const float* __restrict__ b2,
    const float* __restrict__ b3, const float* __restrict__ b4,
    const uint32_t* __restrict__ fk, const float* __restrict__ cst,
    float* __restrict__ out) {
  __shared__ bf16 xb[WG_ROWS * XB_STRIDE];
  __shared__ bf16 hbA[WG_ROWS * H_STRIDE];
  __shared__ bf16 hbB[WG_ROWS * H_STRIDE];

  const int tid  = threadIdx.x;
  const int wave = tid >> 6;
  const int lane = tid & 63;
  const int m    = lane & 15, q = lane >> 4;
  const int r0   = blockIdx.x * WG_ROWS;
  const int c0   = wave * 32;               // col slice, layers 1-3
  const int ntG  = wave * 2;                // first 16-col tile index

  const int mtile4 = wave >> 3;
  const int ntile4 = wave & 7;
  const int xcol   = ntile4 * 16 + m;
  const int xrow0  = mtile4 * 16 + q * 4;

  // ---- init: stage x_init(bf16)->xb, cond(bf16)->hbA, x-state->regs ----
  {
    const int row = tid >> 5;
    const int c4  = (tid & 31) * 4;
    float4 a = *(const float4*)(xinit + (size_t)(r0 + row) * 128 + c4);
    float4 c = *(const float4*)(cond  + (size_t)(r0 + row) * 128 + c4);
    bf16x4 x4, c4v;
    x4[0] = (bf16)a.x; x4[1] = (bf16)a.y; x4[2] = (bf16)a.z; x4[3] = (bf16)a.w;
    c4v[0] = (bf16)c.x; c4v[1] = (bf16)c.y; c4v[2] = (bf16)c.z; c4v[3] = (bf16)c.w;
    *(bf16x4*)(xb  + row * XB_STRIDE + c4) = x4;
    *(bf16x4*)(hbA + row * H_STRIDE  + c4) = c4v;
  }
  float xreg[4];
#pragma unroll
  for (int r = 0; r < 4; ++r)
    xreg[r] = xinit[(size_t)(r0 + xrow0 + r) * 128 + xcol];
  __syncthreads();

  // ---- cproj = cond @ W1[128:256,:] (acc layout matches layer 1) ----
  floatx4 cpr[2][2] = {};
  gemm2<4, 2, H_STRIDE, 4>(hbA, w1cp + ntG * 4 * 512, lane, cpr);
  __syncthreads();  // cond reads done; hbA free

  for (int t = NSTEPS - 1; t >= 0; --t) {
    // ---- layer 1: hbA = gelu(x@W1[:128] + cproj + eb1[t]) ----
    {
      floatx4 acc[2][2] = {};
      gemm2<4, 2, XB_STRIDE, 4>(xb, w1p + ntG * 4 * 512, lane, acc);
      const float* ebt = eb1 + t * 512;
#pragma unroll
      for (int nt = 0; nt < 2; ++nt) {
        const int col = c0 + nt * 16 + m;
        const float bb = ebt[col];
#pragma unroll
        for (int mt = 0; mt < 2; ++mt)
#pragma unroll
          for (int r = 0; r < 4; ++r) {
            const int row = mt * 16 + q * 4 + r;
            hbA[row * H_STRIDE + col] = (bf16)gelu_fast(acc[mt][nt][r] + cpr[mt][nt][r] + bb);
          }
      }
    }
    __syncthreads();  // B1

    // ---- layer 2: hbB = gelu(hbA@W2 + b2) ----
    {
      floatx4 acc[2][2] = {};
      gemm2<16, 2, H_STRIDE, 4>(hbA, w2p + ntG * 16 * 512, lane, acc);
#pragma unroll
      for (int nt = 0; nt < 2; ++nt) {
        const int col = c0 + nt * 16 + m;
        const float bb = b2[col];
#pragma unroll
        for (int mt = 0; mt < 2; ++mt)
#pragma unroll
          for (int r = 0; r < 4; ++r) {
            const int row = mt * 16 + q * 4 + r;
            hbB[row * H_STRIDE + col] = (bf16)gelu_fast(acc[mt][nt][r] + bb);
          }
      }
    }
    __syncthreads();  // B2

    // ---- layer 3: hbA = gelu(hbB@W3 + b3) ----
    {
      floatx4 acc[2][2] = {};
      gemm2<16, 2, H_STRIDE, 4>(hbB, w3p + ntG * 16 * 512, lane, acc);
#pragma unroll
      for (int nt = 0; nt < 2; ++nt) {
        const int col = c0 + nt * 16 + m;
        const float bb = b3[col];
#pragma unroll
        for (int mt = 0; mt < 2; ++mt)
#pragma unroll
          for (int r = 0; r < 4; ++r) {
            const int row = mt * 16 + q * 4 + r;
            hbA[row * H_STRIDE + col] = (bf16)gelu_fast(acc[mt][nt][r] + bb);
          }
      }
    }
    __syncthreads();  // B3

    // ---- layer 4 + DDPM update ----
    {
      floatx4 acc = {};
      gemm1<16, H_STRIDE>(hbA + mtile4 * 16 * H_STRIDE,
                          w4p + ntile4 * 16 * 512, lane, acc);
      const float c1 = cst[t], c2 = cst[NSTEPS + t], c3 = cst[2 * NSTEPS + t];
      const uint32_t fk0 = fk[t], fk1 = fk[NSTEPS + t];
      const float bb = b4[xcol];
#pragma unroll
      for (int r = 0; r < 4; ++r) {
        const int row = xrow0 + r;
        float np = acc[r] + bb;
        float z = 0.0f;
        if (t > 0) {
          uint32_t gidx = (uint32_t)(r0 + row) * 128u + (uint32_t)xcol;
          uint32_t o0, o1;
          threefry2x32(fk0, fk1, 0u, gidx, o0, o1);
          uint32_t bits = o0 ^ o1;
          float f01 = __uint_as_float((bits >> 9) | 0x3F800000u) - 1.0f;
          float u = f01 * 2.0f + (-0.99999994f);
          u = fmaxf(-0.99999994f, u);
          z = 1.4142135381698608f * erfinv_xla(u);
        }
        float xn = (xreg[r] - c1 * np) * c2 + c3 * z;
        xreg[r] = xn;
        xb[row * XB_STRIDE + xcol] = (bf16)xn;
      }
    }
    __syncthreads();  // B4
  }

  // ---- writeout from registers ----
#pragma unroll
  for (int r = 0; r < 4; ++r)
    out[(size_t)(r0 + xrow0 + r) * 128 + xcol] = xreg[r];
}

// ---------------------------------------------------------------------------
extern "C" void kernel_launch(void* const* d_in, const int* in_sizes, int n_in,
                              void* d_out, int out_size, void* d_ws, size_t ws_size,
                              hipStream_t stream) {
  const float* cond  = (const float*)d_in[0];
  const float* xinit = (const float*)d_in[1];
  const float* W1 = (const float*)d_in[2];
  const float* b1 = (const float*)d_in[3];
  const float* W2 = (const float*)d_in[4];
  const float* b2 = (const float*)d_in[5];
  const float* W3 = (const float*)d_in[6];
  const float* b3 = (const float*)d_in[7];
  const float* W4 = (const float*)d_in[8];
  const float* b4 = (const float*)d_in[9];
  const int* tsurv = (const int*)d_in[10];

  char* ws = (char*)d_ws;
  bf16* w1p  = (bf16*)(ws + 0);              // 512*128*2 = 131072
  bf16* w1cp = (bf16*)(ws + 131072);         // 131072
  bf16* w2p  = (bf16*)(ws + 262144);         // 512*512*2 = 524288
  bf16* w3p  = (bf16*)(ws + 786432);         // 524288
  bf16* w4p  = (bf16*)(ws + 1310720);        // 128*512*2 = 131072
  float* eb1 = (float*)(ws + 1441792);       // 50*512*4 = 102400
  uint32_t* fkp = (uint32_t*)(ws + 1544192); // 100*4
  float* cstp = (float*)(ws + 1544704);      // 150*4

  diff_prep<<<1024, 256, 0, stream>>>(W1, b1, W2, W3, W4, tsurv,
                                      w1p, w1cp, w2p, w3p, w4p, eb1, fkp, cstp);
  diff_main<<<256, 1024, 0, stream>>>(cond, xinit, w1p, w1cp, w2p, w3p, w4p,
                                      eb1, b2, b3, b4, fkp, cstp, (float*)d_out);
}

// Round 6
// 995.201 us; speedup vs baseline: 6.7766x; 1.2621x over previous
//
#include <hip/hip_runtime.h>
#include <stdint.h>
#include <stddef.h>

// ---------------------------------------------------------------------------
// CounterfactualDiffusion: 50 sequential steps of 4-layer MLP (258->512->512
// ->512->128) + DDPM update with JAX partitionable-threefry noise, batch 8192.
// Persistent kernel: 256 WGs x 1024 threads (16 waves), each WG owns 32 rows.
// R5 win kept: weights packed in MFMA-fragment order -> wave-contiguous 1KB
// bursts from L2. R6: TRANSPOSED dataflow — W is the MFMA A-operand,
// activations (h^T) are the B-operand. C-layout then hands each lane 4
// consecutive hidden-cols at one batch row: epilogue LDS writes become
// ds_write_b64 (was 16x ds_write_b16), biases/x-state/out go float4.
// Native v_exp/v_log transcendentals (libm exp2f/log1pf were the VALU hogs).
// ---------------------------------------------------------------------------

typedef __bf16 bf16;
typedef __bf16 bf16x4 __attribute__((ext_vector_type(4)));
typedef __bf16 bf16x8 __attribute__((ext_vector_type(8)));
typedef float  floatx4 __attribute__((ext_vector_type(4)));

#define NSTEPS    50
#define WG_ROWS   32
#define XB_STRIDE 136   // 128 + 8 pad
#define H_STRIDE  520   // 512 + 8 pad

__device__ __forceinline__ uint32_t rotl32(uint32_t x, int r) {
  return (x << r) | (x >> (32 - r));
}

// JAX threefry-2x32, 20 rounds.
__device__ __forceinline__ void threefry2x32(uint32_t k0, uint32_t k1,
                                             uint32_t x0, uint32_t x1,
                                             uint32_t& o0, uint32_t& o1) {
  uint32_t k2 = k0 ^ k1 ^ 0x1BD11BDAu;
  x0 += k0; x1 += k1;
#define TF_R(R) { x0 += x1; x1 = rotl32(x1, R); x1 ^= x0; }
  TF_R(13) TF_R(15) TF_R(26) TF_R(6)
  x0 += k1; x1 += k2 + 1u;
  TF_R(17) TF_R(29) TF_R(16) TF_R(24)
  x0 += k2; x1 += k0 + 2u;
  TF_R(13) TF_R(15) TF_R(26) TF_R(6)
  x0 += k0; x1 += k1 + 3u;
  TF_R(17) TF_R(29) TF_R(16) TF_R(24)
  x0 += k1; x1 += k2 + 4u;
  TF_R(13) TF_R(15) TF_R(26) TF_R(6)
  x0 += k2; x1 += k0 + 5u;
#undef TF_R
  o0 = x0; o1 = x1;
}

// XLA's ErfInv32 (Giles). log1p(-x^2) -> ln2 * v_log_f32(fma(-x,x,1)):
// the fma form is cancellation-free; |diff| << bf16 eps.
__device__ __forceinline__ float erfinv_xla(float x) {
  float w = -0.6931471805599453f * __builtin_amdgcn_logf(fmaf(-x, x, 1.0f));
  float p;
  if (w < 5.0f) {
    w -= 2.5f;
    p = 2.81022636e-08f;
    p = fmaf(p, w, 3.43273939e-07f);
    p = fmaf(p, w, -3.5233877e-06f);
    p = fmaf(p, w, -4.39150654e-06f);
    p = fmaf(p, w, 0.00021858087f);
    p = fmaf(p, w, -0.00125372503f);
    p = fmaf(p, w, -0.00417768164f);
    p = fmaf(p, w, 0.246640727f);
    p = fmaf(p, w, 1.50140941f);
  } else {
    w = __builtin_amdgcn_sqrtf(w) - 3.0f;
    p = -0.000200214257f;
    p = fmaf(p, w, 0.000100950558f);
    p = fmaf(p, w, 0.00134934322f);
    p = fmaf(p, w, -0.00367342844f);
    p = fmaf(p, w, 0.00573950773f);
    p = fmaf(p, w, -0.0076224613f);
    p = fmaf(p, w, 0.00943887047f);
    p = fmaf(p, w, 1.00167406f);
    p = fmaf(p, w, 2.83297682f);
  }
  return p * x;
}

// Fast GELU: erf via A&S 7.1.26 (|err|<=1.5e-7), native v_exp_f32.
__device__ __forceinline__ float gelu_fast(float x) {
  float z  = x * 0.7071067811865475f;
  float az = fabsf(z);
  float t  = __builtin_amdgcn_rcpf(fmaf(0.3275911f, az, 1.0f));
  float p  = fmaf(1.061405429f, t, -1.453152027f);
  p = fmaf(p, t, 1.421413741f);
  p = fmaf(p, t, -0.284496736f);
  p = fmaf(p, t, 0.254829592f);
  p *= t;
  float e  = __builtin_amdgcn_exp2f(az * az * -1.4426950408889634f);
  float er = fmaf(-p, e, 1.0f);
  er = copysignf(er, z);
  return 0.5f * x * (1.0f + er);
}

// Transposed MFMA micro-GEMM: D[m][n] = sum_k W^T[m][k] * h^T[k][n].
// A-frag = packed weights (wave-contiguous 1KB bursts, mtile-major),
// B-frag = activations from LDS row-major [32][BSTRIDE] (h^T[k][n]=h[n][k]).
// 2 mtiles x 2 ntiles per wave; each A/B frag shared by 2 MFMAs.
template<int KSTEPS, int BSTRIDE, int UNROLL>
__device__ __forceinline__ void gemm2t(const bf16* __restrict__ h_lds,
                                       const bf16* __restrict__ A_pk,
                                       int lane, floatx4 (&acc)[2][2]) {
  const int nrow = lane & 15, q = lane >> 4;
  const bf16* b0 = h_lds + nrow * BSTRIDE + q * 8;
  const bf16* a0 = A_pk + lane * 8;
#pragma unroll UNROLL
  for (int ks = 0; ks < KSTEPS; ++ks) {
    bf16x8 bf0 = *(const bf16x8*)(b0 + ks * 32);
    bf16x8 bf1 = *(const bf16x8*)(b0 + 16 * BSTRIDE + ks * 32);
    bf16x8 aA  = *(const bf16x8*)(a0 + ks * 512);
    bf16x8 aB  = *(const bf16x8*)(a0 + (KSTEPS + ks) * 512);
    acc[0][0] = __builtin_amdgcn_mfma_f32_16x16x32_bf16(aA, bf0, acc[0][0], 0, 0, 0);
    acc[0][1] = __builtin_amdgcn_mfma_f32_16x16x32_bf16(aA, bf1, acc[0][1], 0, 0, 0);
    acc[1][0] = __builtin_amdgcn_mfma_f32_16x16x32_bf16(aB, bf0, acc[1][0], 0, 0, 0);
    acc[1][1] = __builtin_amdgcn_mfma_f32_16x16x32_bf16(aB, bf1, acc[1][1], 0, 0, 0);
  }
}

// Single-tile variant (layer 4): D[m][n], one mtile x one ntile.
template<int KSTEPS, int BSTRIDE>
__device__ __forceinline__ void gemm1t(const bf16* __restrict__ h_lds,
                                       const bf16* __restrict__ A_pk,
                                       int lane, floatx4& acc) {
  const int nrow = lane & 15, q = lane >> 4;
  const bf16* b0 = h_lds + nrow * BSTRIDE + q * 8;
  const bf16* a0 = A_pk + lane * 8;
#pragma unroll 4
  for (int ks = 0; ks < KSTEPS; ++ks) {
    bf16x8 bfr = *(const bf16x8*)(b0 + ks * 32);
    bf16x8 af  = *(const bf16x8*)(a0 + ks * 512);
    acc = __builtin_amdgcn_mfma_f32_16x16x32_bf16(af, bfr, acc, 0, 0, 0);
  }
}

// ---------------------------------------------------------------------------
// Prep (unchanged from R5): pack weights bf16 fragment-order; per-step L1
// bias; step consts; folded keys. Packed index i = ((mt*KS+ks)*64+lane)*8+j
// maps to hidden-col mt*16+(lane&15), k = ks*32+(lane>>4)*8+j.
// ---------------------------------------------------------------------------
__global__ void diff_prep(const float* __restrict__ W1, const float* __restrict__ b1,
                          const float* __restrict__ W2, const float* __restrict__ W3,
                          const float* __restrict__ W4, const int* __restrict__ tsurv,
                          bf16* __restrict__ w1p, bf16* __restrict__ w1cp,
                          bf16* __restrict__ w2p, bf16* __restrict__ w3p,
                          bf16* __restrict__ w4p,
                          float* __restrict__ eb1, uint32_t* __restrict__ fk,
                          float* __restrict__ cst) {
  const int tid = blockIdx.x * blockDim.x + threadIdx.x;
  const int nth = gridDim.x * blockDim.x;
  for (int i = tid; i < 512 * 128; i += nth) {
    int j = i & 7, lane = (i >> 3) & 63, ks = (i >> 9) & 3, ntg = i >> 11;
    int n = ntg * 16 + (lane & 15);
    int k = ks * 32 + (lane >> 4) * 8 + j;
    w1p[i]  = (bf16)W1[k * 512 + n];
    w1cp[i] = (bf16)W1[(128 + k) * 512 + n];
  }
  for (int i = tid; i < 512 * 512; i += nth) {
    int j = i & 7, lane = (i >> 3) & 63, ks = (i >> 9) & 15, ntg = i >> 13;
    int n = ntg * 16 + (lane & 15);
    int k = ks * 32 + (lane >> 4) * 8 + j;
    w2p[i] = (bf16)W2[k * 512 + n];
    w3p[i] = (bf16)W3[k * 512 + n];
  }
  for (int i = tid; i < 128 * 512; i += nth) {
    int j = i & 7, lane = (i >> 3) & 63, ks = (i >> 9) & 15, ntg = i >> 13;
    int n = ntg * 16 + (lane & 15);
    int k = ks * 32 + (lane >> 4) * 8 + j;
    w4p[i] = (bf16)W4[k * 128 + n];
  }
  const float tgt = (tsurv[0] != 0) ? 0.0f : 1.0f;
  for (int i = tid; i < NSTEPS * 512; i += nth) {
    int t = i >> 9, n = i & 511;
    eb1[i] = b1[n] + ((float)t / 50.0f) * W1[256 * 512 + n] + tgt * W1[257 * 512 + n];
  }
  if (tid == 0) {
    float ac = 1.0f;
    for (int t = 0; t < NSTEPS; ++t) {
      float beta  = 1e-4f + (0.02f - 1e-4f) * ((float)t / 49.0f);
      float alpha = 1.0f - beta;
      ac *= alpha;
      cst[t]            = beta / sqrtf(1.0f - ac);
      cst[NSTEPS + t]   = 1.0f / sqrtf(alpha);
      cst[2*NSTEPS + t] = sqrtf(beta);
      uint32_t o0, o1;
      threefry2x32(0u, 42u, 0u, (uint32_t)t, o0, o1);  // fold_in(key(42), t)
      fk[t] = o0; fk[NSTEPS + t] = o1;
    }
  }
}

// ---------------------------------------------------------------------------
// Main persistent kernel: 256 WGs x 1024 threads, 16 waves.
// Layers 1-3 (transposed): wave w owns hidden-cols [w*32,(w+1)*32) x all 32
// batch rows (2 ntiles). Lane output: 4 consecutive cols at one batch row ->
// ds_write_b64. Layer 4: mtile4 = w&7 (x-cols), ntile4 = w>>3 (row half);
// lane owns 4 consecutive x-cols -> float4 out, ds_write_b64 xb.
// hbA/hbB double-buffer, 4 barriers/step. LDS 73.5KB.
// ---------------------------------------------------------------------------
__global__ __launch_bounds__(1024, 4) void diff_main(
    const float* __restrict__ cond, const float* __restrict__ xinit,
    const bf16* __restrict__ w1p, const bf16* __restrict__ w1cp,
    const bf16* __restrict__ w2p, const bf16* __restrict__ w3p,
    const bf16* __restrict__ w4p,
    const float* __restrict__ eb1, const float* __restrict__ b2,
    const float* __restrict__ b3, const float* __restrict__ b4,
    const uint32_t* __restrict__ fk, const float* __restrict__ cst,
    float* __restrict__ out) {
  __shared__ bf16 xb[WG_ROWS * XB_STRIDE];
  __shared__ bf16 hbA[WG_ROWS * H_STRIDE];
  __shared__ bf16 hbB[WG_ROWS * H_STRIDE];

  const int tid  = threadIdx.x;
  const int wave = tid >> 6;
  const int lane = tid & 63;
  const int nrow = lane & 15, q = lane >> 4;
  const int r0   = blockIdx.x * WG_ROWS;
  const int mc0  = wave * 32;               // hidden-col slice base (L1-3)
  const int qc   = q * 4;                   // lane's 4-col group within a tile

  const int mtile4 = wave & 7;              // L4: x-col tile
  const int ntile4 = wave >> 3;             // L4: batch-row half
  const int n4     = ntile4 * 16 + nrow;    // L4 lane's batch row (local)
  const int xc0    = mtile4 * 16 + qc;      // L4 lane's first x-col

  // ---- init: stage x_init(bf16)->xb, cond(bf16)->hbA, x-state->regs ----
  {
    const int row = tid >> 5;
    const int c4  = (tid & 31) * 4;
    float4 a = *(const float4*)(xinit + (size_t)(r0 + row) * 128 + c4);
    float4 c = *(const float4*)(cond  + (size_t)(r0 + row) * 128 + c4);
    bf16x4 x4, c4v;
    x4[0] = (bf16)a.x; x4[1] = (bf16)a.y; x4[2] = (bf16)a.z; x4[3] = (bf16)a.w;
    c4v[0] = (bf16)c.x; c4v[1] = (bf16)c.y; c4v[2] = (bf16)c.z; c4v[3] = (bf16)c.w;
    *(bf16x4*)(xb  + row * XB_STRIDE + c4) = x4;
    *(bf16x4*)(hbA + row * H_STRIDE  + c4) = c4v;
  }
  float4 xreg = *(const float4*)(xinit + (size_t)(r0 + n4) * 128 + xc0);
  __syncthreads();

  // ---- cproj = (cond @ W1[128:256,:])^T — acc layout matches layer 1 ----
  floatx4 cpr[2][2] = {};
  gemm2t<4, H_STRIDE, 4>(hbA, w1cp + (wave * 2) * 4 * 512, lane, cpr);
  __syncthreads();  // cond reads done; hbA free

  for (int t = NSTEPS - 1; t >= 0; --t) {
    // ---- layer 1: hbA = gelu(x@W1[:128] + cproj + eb1[t]) (transposed) ----
    {
      floatx4 acc[2][2] = {};
      gemm2t<4, XB_STRIDE, 4>(xb, w1p + (wave * 2) * 4 * 512, lane, acc);
      const float* ebt = eb1 + t * 512;
#pragma unroll
      for (int mt = 0; mt < 2; ++mt) {
        const int col = mc0 + mt * 16 + qc;
        float4 bb = *(const float4*)(ebt + col);
#pragma unroll
        for (int nt = 0; nt < 2; ++nt) {
          bf16x4 g;
#pragma unroll
          for (int r = 0; r < 4; ++r)
            g[r] = (bf16)gelu_fast(acc[mt][nt][r] + cpr[mt][nt][r] + ((const float*)&bb)[r]);
          *(bf16x4*)(hbA + (nt * 16 + nrow) * H_STRIDE + col) = g;
        }
      }
    }
    __syncthreads();  // B1

    // ---- layer 2: hbB = gelu(hbA@W2 + b2) ----
    {
      floatx4 acc[2][2] = {};
      gemm2t<16, H_STRIDE, 4>(hbA, w2p + (wave * 2) * 16 * 512, lane, acc);
#pragma unroll
      for (int mt = 0; mt < 2; ++mt) {
        const int col = mc0 + mt * 16 + qc;
        float4 bb = *(const float4*)(b2 + col);
#pragma unroll
        for (int nt = 0; nt < 2; ++nt) {
          bf16x4 g;
#pragma unroll
          for (int r = 0; r < 4; ++r)
            g[r] = (bf16)gelu_fast(acc[mt][nt][r] + ((const float*)&bb)[r]);
          *(bf16x4*)(hbB + (nt * 16 + nrow) * H_STRIDE + col) = g;
        }
      }
    }
    __syncthreads();  // B2

    // ---- layer 3: hbA = gelu(hbB@W3 + b3) ----
    {
      floatx4 acc[2][2] = {};
      gemm2t<16, H_STRIDE, 4>(hbB, w3p + (wave * 2) * 16 * 512, lane, acc);
#pragma unroll
      for (int mt = 0; mt < 2; ++mt) {
        const int col = mc0 + mt * 16 + qc;
        float4 bb = *(const float4*)(b3 + col);
#pragma unroll
        for (int nt = 0; nt < 2; ++nt) {
          bf16x4 g;
#pragma unroll
          for (int r = 0; r < 4; ++r)
            g[r] = (bf16)gelu_fast(acc[mt][nt][r] + ((const float*)&bb)[r]);
          *(bf16x4*)(hbA + (nt * 16 + nrow) * H_STRIDE + col) = g;
        }
      }
    }
    __syncthreads();  // B3

    // ---- layer 4 + DDPM update: lane owns 4 consecutive x-cols, 1 row ----
    {
      floatx4 acc = {};
      gemm1t<16, H_STRIDE>(hbA + ntile4 * 16 * H_STRIDE,
                           w4p + mtile4 * 16 * 512, lane, acc);
      const float c1 = cst[t], c2 = cst[NSTEPS + t], c3 = cst[2 * NSTEPS + t];
      const uint32_t fk0 = fk[t], fk1 = fk[NSTEPS + t];
      float4 bb = *(const float4*)(b4 + xc0);
      const uint32_t gbase = (uint32_t)(r0 + n4) * 128u + (uint32_t)xc0;
      bf16x4 xpk;
#pragma unroll
      for (int r = 0; r < 4; ++r) {
        float np = acc[r] + ((const float*)&bb)[r];
        float z = 0.0f;
        if (t > 0) {
          uint32_t o0, o1;
          threefry2x32(fk0, fk1, 0u, gbase + (uint32_t)r, o0, o1);
          uint32_t bits = o0 ^ o1;
          float f01 = __uint_as_float((bits >> 9) | 0x3F800000u) - 1.0f;
          float u = f01 * 2.0f + (-0.99999994f);
          u = fmaxf(-0.99999994f, u);
          z = 1.4142135381698608f * erfinv_xla(u);
        }
        float xn = (((float*)&xreg)[r] - c1 * np) * c2 + c3 * z;
        ((float*)&xreg)[r] = xn;
        xpk[r] = (bf16)xn;
      }
      *(bf16x4*)(xb + n4 * XB_STRIDE + xc0) = xpk;
    }
    __syncthreads();  // B4
  }

  // ---- writeout: 4 consecutive floats per lane ----
  *(float4*)(out + (size_t)(r0 + n4) * 128 + xc0) = xreg;
}

// ---------------------------------------------------------------------------
extern "C" void kernel_launch(void* const* d_in, const int* in_sizes, int n_in,
                              void* d_out, int out_size, void* d_ws, size_t ws_size,
                              hipStream_t stream) {
  const float* cond  = (const float*)d_in[0];
  const float* xinit = (const float*)d_in[1];
  const float* W1 = (const float*)d_in[2];
  const float* b1 = (const float*)d_in[3];
  const float* W2 = (const float*)d_in[4];
  const float* b2 = (const float*)d_in[5];
  const float* W3 = (const float*)d_in[6];
  const float* b3 = (const float*)d_in[7];
  const float* W4 = (const float*)d_in[8];
  const float* b4 = (const float*)d_in[9];
  const int* tsurv = (const int*)d_in[10];

  char* ws = (char*)d_ws;
  bf16* w1p  = (bf16*)(ws + 0);              // 512*128*2 = 131072
  bf16* w1cp = (bf16*)(ws + 131072);         // 131072
  bf16* w2p  = (bf16*)(ws + 262144);         // 512*512*2 = 524288
  bf16* w3p  = (bf16*)(ws + 786432);         // 524288
  bf16* w4p  = (bf16*)(ws + 1310720);        // 128*512*2 = 131072
  float* eb1 = (float*)(ws + 1441792);       // 50*512*4 = 102400
  uint32_t* fkp = (uint32_t*)(ws + 1544192); // 100*4
  float* cstp = (float*)(ws + 1544704);      // 150*4

  diff_prep<<<1024, 256, 0, stream>>>(W1, b1, W2, W3, W4, tsurv,
                                      w1p, w1cp, w2p, w3p, w4p, eb1, fkp, cstp);
  diff_main<<<256, 1024, 0, stream>>>(cond, xinit, w1p, w1cp, w2p, w3p, w4p,
                                      eb1, b2, b3, b4, fkp, cstp, (float*)d_out);
}